// Round 6
// baseline (381.325 us; speedup 1.0000x reference)
//
#include <hip/hip_runtime.h>

#define B_  64
#define K_  256
#define T_  64
#define DF_ 768
#define N_  1024

typedef __attribute__((ext_vector_type(8))) _Float16 f16x8;
typedef __attribute__((ext_vector_type(4))) float f32x4;

__device__ __forceinline__ unsigned pkrtz(float x, float y) {
    auto h = __builtin_amdgcn_cvt_pkrtz(x, y);    // v_cvt_pkrtz_f16_f32: low=x, high=y
    unsigned u; __builtin_memcpy(&u, &h, 4);
    return u;
}
__device__ __forceinline__ unsigned short h_rne(float x) {
    _Float16 h = (_Float16)x;                     // v_cvt_f16_f32 (RNE)
    unsigned short u; __builtin_memcpy(&u, &h, 2);
    return u;
}
// split x into fp16 hi + fp16 lo (x ≈ hi + lo, residual ~2^-21 rel)
__device__ __forceinline__ void h_split(float x, unsigned short& hs, unsigned short& ls) {
    _Float16 h = (_Float16)x;
    _Float16 l = (_Float16)(x - (float)h);
    __builtin_memcpy(&hs, &h, 2);
    __builtin_memcpy(&ls, &l, 2);
}
// split pair (x,y) into packed-hi u32 and packed-lo u32
__device__ __forceinline__ void pk_split(float x, float y, unsigned& hp, unsigned& lp) {
    auto h = __builtin_amdgcn_cvt_pkrtz(x, y);
    float xh = (float)h[0], yh = (float)h[1];
    auto l = __builtin_amdgcn_cvt_pkrtz(x - xh, y - yh);
    __builtin_memcpy(&hp, &h, 4);
    __builtin_memcpy(&lp, &l, 4);
}

// ---------------------------------------------------------------------------
// prep_we: blocks [0,768): W[d][k] -> W_hi/W_lo [d][k] fp16 split, WT [k][d]
//          blocks [768,1024): e[b][k][t] -> eT_hi/eT_lo [b][t][k] fp16 split
// ---------------------------------------------------------------------------
__global__ __launch_bounds__(256) void prep_we(const float* __restrict__ W,
                                               const float* __restrict__ e,
                                               unsigned short* __restrict__ W_hi,
                                               unsigned short* __restrict__ W_lo,
                                               unsigned short* __restrict__ WT,
                                               unsigned short* __restrict__ eT_hi,
                                               unsigned short* __restrict__ eT_lo) {
    int blk = blockIdx.x;
    if (blk < DF_) {
        int d = blk, k = threadIdx.x;
        unsigned short hs, ls;
        h_split(W[d * K_ + k], hs, ls);
        W_hi[d * K_ + k]  = hs;
        W_lo[d * K_ + k]  = ls;
        WT[k * DF_ + d]   = hs;
    } else {
        int q = blk - DF_;            // [0,256)
        int b = q >> 2, kq = q & 3;
        int t = threadIdx.x & 63, ko = threadIdx.x >> 6;
        const float* eb = e + (size_t)b * K_ * T_;
        unsigned short* eh = eT_hi + (size_t)b * T_ * K_;
        unsigned short* el = eT_lo + (size_t)b * T_ * K_;
#pragma unroll
        for (int i = 0; i < 16; i++) {
            int k = kq * 64 + ko * 16 + i;
            unsigned short hs, ls;
            h_split(eb[k * T_ + t], hs, ls);   // read coalesced over t
            eh[t * K_ + k] = hs;
            el[t * K_ + k] = ls;
        }
    }
}

// ---------------------------------------------------------------------------
// gemm_g: gT[t][d] = sum_k e[k][t]*W[d][k]   (split-fp16, 3-pass MFMA)
// grid (DF/64, B) = 768 blocks, tile [64t x 64d], BK=32. Output split gh/gl.
// ---------------------------------------------------------------------------
__global__ __launch_bounds__(256, 2) void gemm_g(const unsigned short* __restrict__ eT_hi,
                                                 const unsigned short* __restrict__ eT_lo,
                                                 const unsigned short* __restrict__ W_hi,
                                                 const unsigned short* __restrict__ W_lo,
                                                 unsigned short* __restrict__ gT_hi,
                                                 unsigned short* __restrict__ gT_lo) {
    __shared__ unsigned short LeH[64 * 40], LeL[64 * 40];
    __shared__ unsigned short LwH[64 * 40], LwL[64 * 40];
    const int dblk = blockIdx.x * 64;
    const int b = blockIdx.y;
    const int tid = threadIdx.x;
    const int lane = tid & 63, w = tid >> 6, q = lane >> 4, l16 = lane & 15;

    const unsigned short* eh = eT_hi + (size_t)b * T_ * K_;
    const unsigned short* el = eT_lo + (size_t)b * T_ * K_;

    f32x4 acc[4];
#pragma unroll
    for (int i = 0; i < 4; i++) acc[i] = (f32x4)(0.f);

    const int tr = tid >> 2, c8 = (tid & 3) * 8;
    for (int k0 = 0; k0 < K_; k0 += 32) {
        *(uint4*)&LeH[tr * 40 + c8] = *(const uint4*)&eh[tr * K_ + k0 + c8];
        *(uint4*)&LeL[tr * 40 + c8] = *(const uint4*)&el[tr * K_ + k0 + c8];
        *(uint4*)&LwH[tr * 40 + c8] = *(const uint4*)&W_hi[(size_t)(dblk + tr) * K_ + k0 + c8];
        *(uint4*)&LwL[tr * 40 + c8] = *(const uint4*)&W_lo[(size_t)(dblk + tr) * K_ + k0 + c8];
        __syncthreads();
        f16x8 aH[4], aL[4], bH, bL;
#pragma unroll
        for (int mt = 0; mt < 4; mt++) {
            aH[mt] = *(const f16x8*)&LeH[(mt * 16 + l16) * 40 + q * 8];
            aL[mt] = *(const f16x8*)&LeL[(mt * 16 + l16) * 40 + q * 8];
        }
        bH = *(const f16x8*)&LwH[(w * 16 + l16) * 40 + q * 8];
        bL = *(const f16x8*)&LwL[(w * 16 + l16) * 40 + q * 8];
#pragma unroll
        for (int mt = 0; mt < 4; mt++) {
            acc[mt] = __builtin_amdgcn_mfma_f32_16x16x32_f16(aH[mt], bH, acc[mt], 0, 0, 0);
            acc[mt] = __builtin_amdgcn_mfma_f32_16x16x32_f16(aH[mt], bL, acc[mt], 0, 0, 0);
            acc[mt] = __builtin_amdgcn_mfma_f32_16x16x32_f16(aL[mt], bH, acc[mt], 0, 0, 0);
        }
        __syncthreads();
    }

    unsigned short* gh = gT_hi + (size_t)b * T_ * DF_;
    unsigned short* gl = gT_lo + (size_t)b * T_ * DF_;
#pragma unroll
    for (int mt = 0; mt < 4; mt++)
#pragma unroll
        for (int r = 0; r < 4; r++) {
            int t = mt * 16 + q * 4 + r;
            int d = dblk + w * 16 + l16;
            unsigned short hs, ls;
            h_split(acc[mt][r], hs, ls);
            gh[t * DF_ + d] = hs;
            gl[t * DF_ + d] = ls;
        }
}

// ---------------------------------------------------------------------------
// gemm_s: s[t][n] = sum_d g[d][t]*f[d][n]   (split-fp16, 3-pass)
// 512 blocks (XCD-swizzled), tile [64t x 128n], BK=32.
// f fp32 -> fp16 hi/lo pairs on the fly, transposed into LDS [n][d];
// lane-rotated scatter keeps bank aliasing at 2-way (free).
// ---------------------------------------------------------------------------
__global__ __launch_bounds__(256, 2) void gemm_s(const unsigned short* __restrict__ gT_hi,
                                                 const unsigned short* __restrict__ gT_lo,
                                                 const float* __restrict__ f,
                                                 float* __restrict__ s) {
    __shared__ unsigned short LgH[64 * 40], LgL[64 * 40];  // [t][d]
    __shared__ unsigned LfH[128 * 20], LfL[128 * 20];      // [n][dp] u32 = fp16 pair

    const int flat = blockIdx.x;                  // 512 blocks
    const int b    = (flat & 7) * 8 + ((flat >> 3) & 7);
    const int nblk = (flat >> 6) * 128;
    const int tid = threadIdx.x;
    const int lane = tid & 63, w = tid >> 6, q = lane >> 4, l16 = lane & 15;

    const unsigned short* gh = gT_hi + (size_t)b * T_ * DF_;
    const unsigned short* gl = gT_lo + (size_t)b * T_ * DF_;

    f32x4 acc[4][2];
#pragma unroll
    for (int i = 0; i < 4; i++)
#pragma unroll
        for (int j = 0; j < 2; j++) acc[i][j] = (f32x4)(0.f);

    const int dp  = tid >> 4;          // d-pair 0..15
    const int nb  = (tid & 15) * 8;    // 8 consecutive n per thread
    const int rot = tid & 7;
    const int tr = tid >> 2, c8 = (tid & 3) * 8;

    for (int d0 = 0; d0 < DF_; d0 += 32) {
        *(uint4*)&LgH[tr * 40 + c8] = *(const uint4*)&gh[tr * DF_ + d0 + c8];
        *(uint4*)&LgL[tr * 40 + c8] = *(const uint4*)&gl[tr * DF_ + d0 + c8];
        {
            const float* fp = f + ((size_t)b * DF_ + d0 + dp * 2) * N_ + nblk + nb;
            float4 x0 = *(const float4*)&fp[0];
            float4 x1 = *(const float4*)&fp[4];
            float4 y0 = *(const float4*)&fp[N_ + 0];
            float4 y1 = *(const float4*)&fp[N_ + 4];
            const float xs[8] = {x0.x, x0.y, x0.z, x0.w, x1.x, x1.y, x1.z, x1.w};
            const float ys[8] = {y0.x, y0.y, y0.z, y0.w, y1.x, y1.y, y1.z, y1.w};
#pragma unroll
            for (int jj = 0; jj < 8; jj++) {
                int j = (jj + rot) & 7;            // rotate: kills bank conflicts
                unsigned hp, lp;
                pk_split(xs[j], ys[j], hp, lp);
                LfH[(nb + j) * 20 + dp] = hp;
                LfL[(nb + j) * 20 + dp] = lp;
            }
        }
        __syncthreads();
        f16x8 aH[4], aL[4], bH[2], bL[2];
#pragma unroll
        for (int mt = 0; mt < 4; mt++) {
            aH[mt] = *(const f16x8*)&LgH[(mt * 16 + l16) * 40 + q * 8];
            aL[mt] = *(const f16x8*)&LgL[(mt * 16 + l16) * 40 + q * 8];
        }
#pragma unroll
        for (int nt = 0; nt < 2; nt++) {
            int nl = w * 32 + nt * 16 + l16;
            bH[nt] = *(const f16x8*)&((const unsigned short*)LfH)[nl * 40 + q * 8];
            bL[nt] = *(const f16x8*)&((const unsigned short*)LfL)[nl * 40 + q * 8];
        }
#pragma unroll
        for (int mt = 0; mt < 4; mt++)
#pragma unroll
            for (int nt = 0; nt < 2; nt++) {
                acc[mt][nt] = __builtin_amdgcn_mfma_f32_16x16x32_f16(aH[mt], bH[nt], acc[mt][nt], 0, 0, 0);
                acc[mt][nt] = __builtin_amdgcn_mfma_f32_16x16x32_f16(aH[mt], bL[nt], acc[mt][nt], 0, 0, 0);
                acc[mt][nt] = __builtin_amdgcn_mfma_f32_16x16x32_f16(aL[mt], bH[nt], acc[mt][nt], 0, 0, 0);
            }
        __syncthreads();
    }

    float* sb = s + (size_t)b * T_ * N_;
#pragma unroll
    for (int mt = 0; mt < 4; mt++)
#pragma unroll
        for (int nt = 0; nt < 2; nt++)
#pragma unroll
            for (int r = 0; r < 4; r++) {
                int t = mt * 16 + q * 4 + r;
                int n = nblk + w * 32 + nt * 16 + l16;
                sb[(size_t)t * N_ + n] = acc[mt][nt][r];
            }
}

// ---------------------------------------------------------------------------
// softmax over n -> fp16 alpha
// ---------------------------------------------------------------------------
__global__ __launch_bounds__(256) void softmax_k(const float* __restrict__ s,
                                                 unsigned short* __restrict__ alpha,
                                                 const float* __restrict__ gptr) {
    const float g = gptr[0];
    const float* row = s + (size_t)blockIdx.x * N_;
    unsigned short* arow = alpha + (size_t)blockIdx.x * N_;
    const int t = threadIdx.x;

    float4 x = *(const float4*)(row + t * 4);
    x.x *= g; x.y *= g; x.z *= g; x.w *= g;

    float m = fmaxf(fmaxf(x.x, x.y), fmaxf(x.z, x.w));
#pragma unroll
    for (int off = 32; off > 0; off >>= 1) m = fmaxf(m, __shfl_xor(m, off, 64));
    __shared__ float sm[4], ss[4];
    int wave = t >> 6;
    if ((t & 63) == 0) sm[wave] = m;
    __syncthreads();
    m = fmaxf(fmaxf(sm[0], sm[1]), fmaxf(sm[2], sm[3]));

    float e0 = __expf(x.x - m), e1 = __expf(x.y - m);
    float e2 = __expf(x.z - m), e3 = __expf(x.w - m);
    float sum = e0 + e1 + e2 + e3;
#pragma unroll
    for (int off = 32; off > 0; off >>= 1) sum += __shfl_xor(sum, off, 64);
    if ((t & 63) == 0) ss[wave] = sum;
    __syncthreads();
    sum = ss[0] + ss[1] + ss[2] + ss[3];
    float inv = 1.f / sum;
    uint2 o;
    o.x = pkrtz(e0 * inv, e1 * inv);
    o.y = pkrtz(e2 * inv, e3 * inv);
    *(uint2*)&arow[t * 4] = o;
}

// ---------------------------------------------------------------------------
// gemm_h: hT[t][d] = sum_n f[d][n]*alpha[t][n]   (fp16 single-pass)
// grid (DF/64, B) = 768 blocks, tile [64d x 64t], BK=64, 3 blocks/CU.
// ---------------------------------------------------------------------------
__global__ __launch_bounds__(256, 3) void gemm_h(const float* __restrict__ f,
                                                 const unsigned short* __restrict__ alpha,
                                                 unsigned short* __restrict__ hT) {
    __shared__ unsigned short Lf[64 * 72];   // [d][n]
    __shared__ unsigned short La[64 * 72];   // [t][n]
    const int dblk = blockIdx.x * 64;
    const int b = blockIdx.y;
    const int tid = threadIdx.x;
    const int lane = tid & 63, w = tid >> 6, q = lane >> 4, l16 = lane & 15;

    const float* fb = f + (size_t)b * DF_ * N_;
    const unsigned short* ab = alpha + (size_t)b * T_ * N_;

    f32x4 acc[4];
#pragma unroll
    for (int i = 0; i < 4; i++) acc[i] = (f32x4)(0.f);

    const int fr_ = tid >> 2, fc = tid & 3;
    for (int n0 = 0; n0 < N_; n0 += 64) {
        const float* frp = fb + (size_t)(dblk + fr_) * N_ + n0 + fc * 16;
#pragma unroll
        for (int i = 0; i < 4; i++) {
            float4 x = *(const float4*)&frp[i * 4];
            uint2 o;
            o.x = pkrtz(x.x, x.y);
            o.y = pkrtz(x.z, x.w);
            *(uint2*)&Lf[fr_ * 72 + fc * 16 + i * 4] = o;
        }
#pragma unroll
        for (int l = 0; l < 2; l++) {
            int idx = tid * 2 + l;
            int r = idx >> 3, c8 = (idx & 7) * 8;
            *(uint4*)&La[r * 72 + c8] = *(const uint4*)&ab[(size_t)r * N_ + n0 + c8];
        }
        __syncthreads();
        f16x8 af[2], bb[4][2];
#pragma unroll
        for (int kk = 0; kk < 2; kk++)
            af[kk] = *(const f16x8*)&Lf[(w * 16 + l16) * 72 + kk * 32 + q * 8];
#pragma unroll
        for (int nt = 0; nt < 4; nt++)
#pragma unroll
            for (int kk = 0; kk < 2; kk++)
                bb[nt][kk] = *(const f16x8*)&La[(nt * 16 + l16) * 72 + kk * 32 + q * 8];
#pragma unroll
        for (int nt = 0; nt < 4; nt++)
#pragma unroll
            for (int kk = 0; kk < 2; kk++)
                acc[nt] = __builtin_amdgcn_mfma_f32_16x16x32_f16(af[kk], bb[nt][kk], acc[nt], 0, 0, 0);
        __syncthreads();
    }

    unsigned short* hb = hT + (size_t)b * T_ * DF_;
#pragma unroll
    for (int nt = 0; nt < 4; nt++)
#pragma unroll
        for (int r = 0; r < 4; r++) {
            int d = dblk + w * 16 + q * 4 + r;
            int t = nt * 16 + l16;
            hb[(size_t)t * DF_ + d] = h_rne(acc[nt][r]);
        }
}

// ---------------------------------------------------------------------------
// gemm_c: c[k][t] = sum_d W[d][k]*h[d][t] + bias[k]   (fp16 single-pass)
// grid (K/64, B) = 256 blocks, tile [64k x 64t], BK=64.
// ---------------------------------------------------------------------------
__global__ __launch_bounds__(256, 2) void gemm_c(const unsigned short* __restrict__ WT,
                                                 const unsigned short* __restrict__ hT,
                                                 const float* __restrict__ bias,
                                                 float* __restrict__ c) {
    __shared__ unsigned short LW[64 * 72];   // [k][d]
    __shared__ unsigned short Lh[64 * 72];   // [t][d]
    const int kblk = blockIdx.x * 64;
    const int b = blockIdx.y;
    const int tid = threadIdx.x;
    const int lane = tid & 63, w = tid >> 6, q = lane >> 4, l16 = lane & 15;

    const unsigned short* hb = hT + (size_t)b * T_ * DF_;

    f32x4 acc[4];
#pragma unroll
    for (int i = 0; i < 4; i++) acc[i] = (f32x4)(0.f);

    for (int d0 = 0; d0 < DF_; d0 += 64) {
#pragma unroll
        for (int l = 0; l < 2; l++) {
            int idx = tid * 2 + l;
            int r = idx >> 3, c8 = (idx & 7) * 8;
            *(uint4*)&LW[r * 72 + c8] = *(const uint4*)&WT[(size_t)(kblk + r) * DF_ + d0 + c8];
            *(uint4*)&Lh[r * 72 + c8] = *(const uint4*)&hb[(size_t)r * DF_ + d0 + c8];
        }
        __syncthreads();
        f16x8 aw[2], bh[4][2];
#pragma unroll
        for (int kk = 0; kk < 2; kk++)
            aw[kk] = *(const f16x8*)&LW[(w * 16 + l16) * 72 + kk * 32 + q * 8];
#pragma unroll
        for (int nt = 0; nt < 4; nt++)
#pragma unroll
            for (int kk = 0; kk < 2; kk++)
                bh[nt][kk] = *(const f16x8*)&Lh[(nt * 16 + l16) * 72 + kk * 32 + q * 8];
#pragma unroll
        for (int nt = 0; nt < 4; nt++)
#pragma unroll
            for (int kk = 0; kk < 2; kk++)
                acc[nt] = __builtin_amdgcn_mfma_f32_16x16x32_f16(aw[kk], bh[nt][kk], acc[nt], 0, 0, 0);
        __syncthreads();
    }

    float* cb = c + (size_t)b * K_ * T_;
#pragma unroll
    for (int nt = 0; nt < 4; nt++)
#pragma unroll
        for (int r = 0; r < 4; r++) {
            int k = kblk + w * 16 + q * 4 + r;
            int t = nt * 16 + l16;
            cb[(size_t)k * T_ + t] = acc[nt][r] + bias[k];
        }
}

// ---------------------------------------------------------------------------
// cos_k: cos[b,i,j] = <c[:,i], e[:,j]> / (|c[:,i]| |e[:,j]|)
// grid (T/4, B), 256 threads: wave iq handles row i = bx*4+iq.
// ---------------------------------------------------------------------------
__global__ __launch_bounds__(256) void cos_k(const float* __restrict__ c,
                                             const float* __restrict__ e,
                                             float* __restrict__ out) {
    const int iq = threadIdx.x >> 6;
    const int i = blockIdx.x * 4 + iq;
    const int b = blockIdx.y;
    const int j = threadIdx.x & 63;
    const float* cb = c + (size_t)b * K_ * T_;
    const float* eb = e + (size_t)b * K_ * T_;

    float dot = 0.f, se = 0.f, sc = 0.f;
#pragma unroll 8
    for (int k = 0; k < K_; k++) {
        float cv = cb[(size_t)k * T_ + i];
        float ev = eb[(size_t)k * T_ + j];
        dot += cv * ev;
        se  += ev * ev;
        sc  += cv * cv;
    }
    out[((size_t)b * T_ + i) * T_ + j] = dot * rsqrtf(sc * se);
}

// ---------------------------------------------------------------------------
extern "C" void kernel_launch(void* const* d_in, const int* in_sizes, int n_in,
                              void* d_out, int out_size, void* d_ws, size_t ws_size,
                              hipStream_t stream) {
    const float* e     = (const float*)d_in[0];  // [B,K,T]
    const float* f     = (const float*)d_in[1];  // [B,DF,N]
    const float* gamma = (const float*)d_in[2];
    const float* W     = (const float*)d_in[3];  // [DF,K]
    const float* bias  = (const float*)d_in[4];  // [K]
    float* out = (float*)d_out;                  // [B,T,T]

    char* p = (char*)d_ws;
    unsigned short* W_hi  = (unsigned short*)p; p += (size_t)DF_ * K_ * 2;
    unsigned short* W_lo  = (unsigned short*)p; p += (size_t)DF_ * K_ * 2;
    unsigned short* WT    = (unsigned short*)p; p += (size_t)DF_ * K_ * 2;
    unsigned short* eT_hi = (unsigned short*)p; p += (size_t)B_ * T_ * K_ * 2;
    unsigned short* eT_lo = (unsigned short*)p; p += (size_t)B_ * T_ * K_ * 2;
    unsigned short* gT_hi = (unsigned short*)p; p += (size_t)B_ * T_ * DF_ * 2;
    unsigned short* gT_lo = (unsigned short*)p; p += (size_t)B_ * T_ * DF_ * 2;
    float*          s     = (float*)p;          p += (size_t)B_ * T_ * N_ * 4;
    unsigned short* alpha = (unsigned short*)p; p += (size_t)B_ * T_ * N_ * 2;
    unsigned short* hT    = (unsigned short*)p; p += (size_t)B_ * T_ * DF_ * 2;
    float*          c     = (float*)p;          p += (size_t)B_ * K_ * T_ * 4;

    prep_we <<<dim3(DF_ + 256),     256, 0, stream>>>(W, e, W_hi, W_lo, WT, eT_hi, eT_lo);
    gemm_g  <<<dim3(DF_ / 64, B_),  256, 0, stream>>>(eT_hi, eT_lo, W_hi, W_lo, gT_hi, gT_lo);
    gemm_s  <<<dim3(512),           256, 0, stream>>>(gT_hi, gT_lo, f, s);
    softmax_k<<<dim3(B_ * T_),      256, 0, stream>>>(s, alpha, gamma);
    gemm_h  <<<dim3(DF_ / 64, B_),  256, 0, stream>>>(f, alpha, hT);
    gemm_c  <<<dim3(K_ / 64, B_),   256, 0, stream>>>(WT, hT, bias, c);
    cos_k   <<<dim3(T_ / 4, B_),    256, 0, stream>>>(c, e, out);
}